// Round 2
// baseline (69.051 us; speedup 1.0000x reference)
//
#include <hip/hip_runtime.h>

// OneHotEncoder: per-row histogram of tokens, skipping pad_idx=0.
// tokens: [B=256, T=2048] int32 ; out: [B, VOCAB=32000] float32.
// Memory-bound on the 32.8 MB output write.
//
// V2.1 structure: vocab-CHUNKED blocks. Each block owns (row, vocab-chunk of 8000):
//  - 16 KB LDS packed 2x16-bit histogram (vs 64 KB full-vocab before)
//  - re-scans the row's 2048 tokens, keeps only in-range ones
//  - streams its 32 KB output slice with nontemporal 16B stores
// Grid 256x4 = 1024 blocks of 256 threads -> ~4 independent blocks/CU
// (was 1 monolithic 1024-thread block/CU), so store phases of different
// blocks overlap instead of serializing behind block-wide barriers.
//
// NOTE: __builtin_nontemporal_store needs a clang vector type, not HIP's
// float4 class -> use ext_vector_type(4) alias for the store.

#define VOCAB  32000
#define CHUNKS 4
#define CV     (VOCAB / CHUNKS)   // 8000 vocab entries per chunk
#define BLOCK  256

typedef float f32x4 __attribute__((ext_vector_type(4)));

__global__ __launch_bounds__(BLOCK)
void OneHotEncoder_43052752175267_kernel(const int* __restrict__ tokens,
                                         float* __restrict__ out,
                                         int T) {
    // Packed histogram: hist[i] holds counts for local tokens 2i (lo 16b), 2i+1 (hi 16b).
    // Max count = T = 2048 < 65536 -> no carry into the neighboring half.
    __shared__ __align__(16) unsigned int hist[CV / 2];   // 4000 u32 = 16 KB

    const int row   = blockIdx.x >> 2;            // CHUNKS == 4
    const int chunk = blockIdx.x & (CHUNKS - 1);
    const int lo    = chunk * CV;
    const int tid   = threadIdx.x;

    // --- Phase 1: zero the LDS histogram (uint4-vectorized) ---
    uint4* h4 = (uint4*)hist;
    const uint4 z = make_uint4(0u, 0u, 0u, 0u);
    for (int i = tid; i < CV / 8; i += BLOCK)     // 1000 uint4
        h4[i] = z;
    __syncthreads();

    // --- Phase 2: scan this row's tokens, DS-atomic the in-range ones ---
    const int* trow = tokens + (long long)row * T;
    for (int i = tid; i < T; i += BLOCK) {        // 8 iters
        int tok = trow[i];
        unsigned local = (unsigned)(tok - lo);
        if (tok != 0 && local < (unsigned)CV)
            atomicAdd(&hist[local >> 1], 1u << ((local & 1) << 4));
    }
    __syncthreads();

    // --- Phase 3: unpack and stream out, nontemporal coalesced 16B stores ---
    // (32.8 MB total output > 32 MB aggregate L2 -> bypass, don't thrash.)
    f32x4* o4 = (f32x4*)(out + (long long)row * VOCAB + lo);
    const uint2* h2 = (const uint2*)hist;
    for (int i = tid; i < CV / 4; i += BLOCK) {   // 2000 f32x4 -> ~8 iters
        uint2 h = h2[i];
        f32x4 f;
        f.x = (float)(h.x & 0xFFFFu);
        f.y = (float)(h.x >> 16);
        f.z = (float)(h.y & 0xFFFFu);
        f.w = (float)(h.y >> 16);
        __builtin_nontemporal_store(f, &o4[i]);
    }
}

extern "C" void kernel_launch(void* const* d_in, const int* in_sizes, int n_in,
                              void* d_out, int out_size, void* d_ws, size_t ws_size,
                              hipStream_t stream) {
    const int* tokens = (const int*)d_in[0];
    // d_in[1] (lengths) is unused by the reference computation.
    const int B = in_sizes[1];           // 256 (lengths has one entry per row)
    const int T = in_sizes[0] / B;       // 2048
    float* out = (float*)d_out;

    OneHotEncoder_43052752175267_kernel<<<dim3(B * CHUNKS), dim3(BLOCK), 0, stream>>>(tokens, out, T);
}